// Round 1
// baseline (7358.405 us; speedup 1.0000x reference)
//
#include <hip/hip_runtime.h>
#include <stdint.h>

#define B_    16
#define CIN   256
#define COUT  128
#define VLOW  10242
#define NUP   40962
#define KTAP  7
#define FTOT  (KTAP * COUT)   // 896

typedef __attribute__((ext_vector_type(4))) float  floatx4;
typedef __attribute__((ext_vector_type(8))) short  bf16x8;

__device__ __forceinline__ unsigned short f2bf(float f) {
    union { float f; unsigned int u; } x; x.f = f;
    unsigned int r = x.u + 0x7FFFu + ((x.u >> 16) & 1u);  // RNE
    return (unsigned short)(r >> 16);
}

__global__ void count_kernel(const int* __restrict__ neigh, int* __restrict__ counts) {
    int i = blockIdx.x * blockDim.x + threadIdx.x;
    if (i < VLOW * KTAP) atomicAdd(&counts[neigh[i]], 1);
}

__global__ void inv_kernel(const int* __restrict__ counts, float* __restrict__ invc) {
    int i = blockIdx.x * blockDim.x + threadIdx.x;
    if (i < NUP) {
        int c = counts[i];
        invc[i] = (c > 0) ? (1.0f / (float)c) : 0.0f;
    }
}

// Block: 256 threads (4 waves). Tile: 128 v  x  128 f (f-tile == one neighbor tap k).
// LDS: A [128 v][40 (32 k + 8 pad)] bf16, B [128 f][40] bf16.
__global__ __launch_bounds__(256)
void gemm_scatter(const float* __restrict__ x,     // [B, CIN, VLOW]
                  const float* __restrict__ w,     // [CIN, FTOT]
                  const float* __restrict__ bias,  // [FTOT]
                  const int*   __restrict__ neigh, // [VLOW*KTAP]
                  const float* __restrict__ invc,  // [NUP]
                  float*       __restrict__ out)   // [B, COUT, NUP]
{
    __shared__ unsigned short lds_a[128 * 40];
    __shared__ unsigned short lds_b[128 * 40];

    const int t    = threadIdx.x;
    const int vt   = blockIdx.x;       // 0..80
    const int ktap = blockIdx.y;       // 0..6
    const int b    = blockIdx.z;       // 0..15
    const int v0   = vt * 128;
    const int f0   = ktap * 128;

    const int lane = t & 63;
    const int wid  = t >> 6;
    const int wv   = wid & 1;          // wave v-half
    const int wf   = wid >> 1;         // wave f-half
    const int mrow = lane & 15;
    const int quad = lane >> 4;
    const int kb   = quad * 8;         // k-offset within 32-chunk for frags

    floatx4 acc[4][4];
#pragma unroll
    for (int i = 0; i < 4; i++)
#pragma unroll
        for (int j = 0; j < 4; j++) acc[i][j] = (floatx4)0.0f;

    // staging mapping: 128 threads over the tile's fast dim, 2 groups of 16 c-rows
    const int sv = t & 127;            // v (A) or f (B) within tile
    const int sc = (t >> 7) * 16;      // c' base: 0 or 16

    const float* xb = x + (size_t)b * CIN * VLOW;
    int vg = v0 + sv; if (vg > VLOW - 1) vg = VLOW - 1;   // clamp (padded rows masked later)

    for (int kc = 0; kc < CIN; kc += 32) {
        float av[16], bv16[16];
#pragma unroll
        for (int cc = 0; cc < 16; cc++) {
            av[cc]   = xb[(size_t)(kc + sc + cc) * VLOW + vg];
            bv16[cc] = w[(size_t)(kc + sc + cc) * FTOT + f0 + sv];
        }
        __syncthreads();   // previous tiles fully consumed
        unsigned int pa[8], pb[8];
#pragma unroll
        for (int q = 0; q < 8; q++) {
            pa[q] = (unsigned int)f2bf(av[2*q])   | ((unsigned int)f2bf(av[2*q+1])   << 16);
            pb[q] = (unsigned int)f2bf(bv16[2*q]) | ((unsigned int)f2bf(bv16[2*q+1]) << 16);
        }
        *(uint4*)&lds_a[sv * 40 + sc]     = make_uint4(pa[0], pa[1], pa[2], pa[3]);
        *(uint4*)&lds_a[sv * 40 + sc + 8] = make_uint4(pa[4], pa[5], pa[6], pa[7]);
        *(uint4*)&lds_b[sv * 40 + sc]     = make_uint4(pb[0], pb[1], pb[2], pb[3]);
        *(uint4*)&lds_b[sv * 40 + sc + 8] = make_uint4(pb[4], pb[5], pb[6], pb[7]);
        __syncthreads();

        bf16x8 fa[4], fb[4];
#pragma unroll
        for (int i = 0; i < 4; i++)
            fa[i] = *(const bf16x8*)&lds_a[(wv * 64 + i * 16 + mrow) * 40 + kb];
#pragma unroll
        for (int j = 0; j < 4; j++)
            fb[j] = *(const bf16x8*)&lds_b[(wf * 64 + j * 16 + mrow) * 40 + kb];
#pragma unroll
        for (int i = 0; i < 4; i++)
#pragma unroll
            for (int j = 0; j < 4; j++)
                acc[i][j] = __builtin_amdgcn_mfma_f32_16x16x32_bf16(fa[i], fb[j], acc[i][j], 0, 0, 0);
    }

    // epilogue: D row = v-local (quad*4+r), col = f-local (lane&15); add bias, scale 1/cnt, scatter
    float bvv[4];
#pragma unroll
    for (int j = 0; j < 4; j++) bvv[j] = bias[f0 + wf * 64 + j * 16 + mrow];

#pragma unroll
    for (int i = 0; i < 4; i++) {
#pragma unroll
        for (int r = 0; r < 4; r++) {
            int v = v0 + wv * 64 + i * 16 + quad * 4 + r;
            if (v >= VLOW) continue;
            int n = neigh[v * KTAP + ktap];
            float s = invc[n];
            size_t obase = (size_t)b * COUT * NUP + (size_t)n;
#pragma unroll
            for (int j = 0; j < 4; j++) {
                int c = wf * 64 + j * 16 + mrow;
                float val = (acc[i][j][r] + bvv[j]) * s;
                atomicAdd(&out[obase + (size_t)c * NUP], val);
            }
        }
    }
}

extern "C" void kernel_launch(void* const* d_in, const int* in_sizes, int n_in,
                              void* d_out, int out_size, void* d_ws, size_t ws_size,
                              hipStream_t stream) {
    const float* x     = (const float*)d_in[0];
    const float* w     = (const float*)d_in[1];
    const float* bias  = (const float*)d_in[2];
    const int*   neigh = (const int*)d_in[3];
    float* out = (float*)d_out;

    int*   counts = (int*)d_ws;
    float* invc   = (float*)((char*)d_ws + ((NUP * 4 + 255) / 256) * 256);

    hipMemsetAsync(d_out, 0, (size_t)out_size * sizeof(float), stream);
    hipMemsetAsync(counts, 0, NUP * sizeof(int), stream);

    count_kernel<<<(VLOW * KTAP + 255) / 256, 256, 0, stream>>>(neigh, counts);
    inv_kernel<<<(NUP + 255) / 256, 256, 0, stream>>>(counts, invc);

    dim3 grid(81, KTAP, B_);
    gemm_scatter<<<grid, 256, 0, stream>>>(x, w, bias, neigh, invc, out);
}